// Round 1
// baseline (709.801 us; speedup 1.0000x reference)
//
#include <hip/hip_runtime.h>
#include <hip/hip_fp16.h>

typedef _Float16 f16;
typedef __attribute__((ext_vector_type(8))) _Float16 f16x8;
typedef __attribute__((ext_vector_type(4))) float f32x4;

// ---------------- workspace layout (bytes) ----------------
#define WS_CET   0u           // ceT  [256][32][16] f16   = 262144
#define WS_WC    262144u      // Wc   [3][512][512] f16   = 1572864
#define WS_W1    1835008u     // W1   [1024][1024] f16    = 2097152
#define WS_U     3932160u     // U    [4096][1024] f16    = 8388608
#define WS_PART  12320768u    // part [32][1024]  f32     = 131072
#define WS_RMAX  12451840u    // rmax [1024]      f32     = 4096
#define WS_H     12455936u    // h    [2048]      f32     = 8192
// total ~12.5 MB

// ---------------- prep kernels ----------------
// ceT[c][l][m] = ce[c][m*32+l]  (zero row for padding_idx=0)
// because x[n, i, l] = ce[char[n, i>>4], (i&15)*32 + l]  (reshape, not transpose)
__global__ __launch_bounds__(512) void k0_ceT(const float* __restrict__ ce,
                                              f16* __restrict__ ceT) {
  int c = blockIdx.x;
  int t = threadIdx.x;             // 512 threads
  int m = t >> 5, l = t & 31;
  float v = (c == 0) ? 0.f : ce[c * 512 + m * 32 + l];
  ceT[c * 512 + l * 16 + m] = (f16)v;
}

// Wc[k][o][i] = conv_chr_w[o][i][k]
__global__ __launch_bounds__(256) void k0_wc(const float* __restrict__ w,
                                             f16* __restrict__ Wc) {
  int e = blockIdx.x * 256 + threadIdx.x;   // 786432 total
  int k = e >> 18, rem = e & 262143;
  int o = rem >> 9, i = rem & 511;
  Wc[e] = (f16)w[(o * 512 + i) * 3 + k];
}

// W1[o][i] = conv_sent_w[o][i][1]  (only center tap touches length-1 input)
__global__ __launch_bounds__(256) void k0_w1(const float* __restrict__ w,
                                             f16* __restrict__ W1) {
  int e = blockIdx.x * 256 + threadIdx.x;   // 1048576 total
  int o = e >> 10, i = e & 1023;
  W1[e] = (f16)w[(o * 1024 + i) * 3 + 1];
}

// U[n][0..511] = word_emb[words[n]] (zero if padding idx 0)
__global__ __launch_bounds__(256) void k0_u(const int* __restrict__ words,
                                            const float* __restrict__ wemb,
                                            f16* __restrict__ U) {
  int n = blockIdx.x;
  int wd = words[n];
  const float* src = wemb + (size_t)wd * 512;
  for (int i = threadIdx.x; i < 512; i += 256) {
    float v = (wd == 0) ? 0.f : src[i];
    U[n * 1024 + i] = (f16)v;
  }
}

// ---------------- k1: char conv + maxpool -> U[n][512..1023] ----------------
// GEMM: M = o (128/block), N = (word,l) (8 words * 32 = 256), K = 512i x 3taps.
// Taps are shifted reads from a halo-padded LDS char tile.
__global__ __launch_bounds__(256) void k1_conv(
    const int* __restrict__ wic, const f16* __restrict__ Wc,
    const f16* __restrict__ ceT, const float* __restrict__ bias,
    f16* __restrict__ U)
{
  __shared__ __align__(16) f16 sA[3 * 128 * 32];   // [tap][o][i] 24 KB, xor-swizzled
  __shared__ __align__(16) f16 sB[8 * 34 * 32];    // [word][l'(halo)][i] 17 KB, xor-swizzled
  __shared__ int   sChar[256];
  __shared__ float sBias[128];

  const int tid = threadIdx.x;
  const int w0 = blockIdx.x * 8;     // word tile
  const int o0 = blockIdx.y * 128;   // out-channel tile
  const int wid = tid >> 6, lane = tid & 63;
  const int wm = wid >> 1, wn = wid & 1;           // 2x2 waves, wave tile 64o x 128col
  const int l15 = lane & 15, g4 = lane >> 4;

  sChar[tid] = wic[w0 * 32 + tid];                 // 8 words x 32 chars
  if (tid < 128) sBias[tid] = bias[o0 + tid];

  f32x4 acc[4][8];
#pragma unroll
  for (int m = 0; m < 4; ++m)
#pragma unroll
    for (int n = 0; n < 8; ++n) acc[m][n] = (f32x4){0.f, 0.f, 0.f, 0.f};

  __syncthreads();

  for (int step = 0; step < 16; ++step) {
    const int i0 = step * 32, gb = step * 2;       // 32 input chans = 2 char groups
    // stage A: 3 taps x 128 o x 32 i, 16B chunks, chunk ^= (o&3)
#pragma unroll
    for (int c = tid; c < 1536; c += 256) {
      int k = c >> 9, rem = c & 511, o = rem >> 2, ch = rem & 3;
      uint4 v = *(const uint4*)(Wc + ((k * 512 + o0 + o) * 512 + i0 + ch * 8));
      *(uint4*)((char*)sA + (((k * 128 + o) * 4 + (ch ^ (o & 3))) << 4)) = v;
    }
    // stage B: 8 words x 34 l'(halo) x 32 i, chunk ^= (l'&3); rows 0/33 are zero halo
    for (int c = tid; c < 1088; c += 256) {
      int w = c / 136, rem = c - w * 136, lp = rem >> 2, ch = rem & 3;
      uint4 v = make_uint4(0u, 0u, 0u, 0u);
      if (lp > 0 && lp < 33) {
        int cc = sChar[(w << 5) + gb + (ch >> 1)];
        v = *(const uint4*)(ceT + (cc * 512 + (lp - 1) * 16 + (ch & 1) * 8));
      }
      *(uint4*)((char*)sB + (((w * 34 + lp) * 4 + (ch ^ (lp & 3))) << 4)) = v;
    }
    __syncthreads();

#pragma unroll
    for (int k = 0; k < 3; ++k) {
      f16x8 a[4];
#pragma unroll
      for (int m = 0; m < 4; ++m) {
        int ol = wm * 64 + m * 16 + l15;
        a[m] = *(const f16x8*)((const char*)sA +
                 (((k * 128 + ol) * 4 + (g4 ^ (ol & 3))) << 4));
      }
#pragma unroll
      for (int n = 0; n < 8; ++n) {
        int w = wn * 4 + (n >> 1);
        int lp = (n & 1) * 16 + l15 + k;           // halo row = l + tap
        f16x8 b = *(const f16x8*)((const char*)sB +
                   (((w * 34 + lp) * 4 + (g4 ^ (lp & 3))) << 4));
#pragma unroll
        for (int m = 0; m < 4; ++m)
          acc[m][n] = __builtin_amdgcn_mfma_f32_16x16x32_f16(a[m], b, acc[m][n], 0, 0, 0);
      }
    }
    __syncthreads();
  }

  // epilogue: max over l (pairs of n-frags + shfl over lane&15), +bias, store f16
#pragma unroll
  for (int m = 0; m < 4; ++m) {
    float vm[16];
#pragma unroll
    for (int wp = 0; wp < 4; ++wp)
#pragma unroll
      for (int j = 0; j < 4; ++j)
        vm[wp * 4 + j] = fmaxf(acc[m][2 * wp][j], acc[m][2 * wp + 1][j]);
#pragma unroll
    for (int off = 1; off <= 8; off <<= 1)
#pragma unroll
      for (int t = 0; t < 16; ++t)
        vm[t] = fmaxf(vm[t], __shfl_xor(vm[t], off));
    float v = vm[0];
#pragma unroll
    for (int t = 1; t < 16; ++t) v = (l15 == t) ? vm[t] : v;  // static-index select
    int ol = wm * 64 + m * 16 + g4 * 4 + (l15 & 3);
    int word = w0 + wn * 4 + (l15 >> 2);
    U[word * 1024 + 512 + o0 + ol] = (f16)(v + sBias[ol]);
  }
}

// ---------------- k2: r = U @ W1^T, column-max over words -> partials ----------
__global__ __launch_bounds__(256) void k2_sent(
    const f16* __restrict__ U, const f16* __restrict__ W1,
    float* __restrict__ part)
{
  __shared__ __align__(16) f16 sA[128 * 32];
  __shared__ __align__(16) f16 sB[128 * 32];
  __shared__ float sRed[2][128];

  const int tid = threadIdx.x;
  const int w0 = blockIdx.x * 128;   // word tile (32 tiles)
  const int o0 = blockIdx.y * 128;   // output tile (8 tiles)
  const int wid = tid >> 6, lane = tid & 63;
  const int wm = wid >> 1, wn = wid & 1;
  const int l15 = lane & 15, g4 = lane >> 4;

  f32x4 acc[4][4];
#pragma unroll
  for (int m = 0; m < 4; ++m)
#pragma unroll
    for (int n = 0; n < 4; ++n) acc[m][n] = (f32x4){0.f, 0.f, 0.f, 0.f};

  for (int step = 0; step < 32; ++step) {
    const int i0 = step * 32;
#pragma unroll
    for (int c = tid; c < 512; c += 256) {
      int r = c >> 2, ch = c & 3;
      uint4 va = *(const uint4*)(U + (w0 + r) * 1024 + i0 + ch * 8);
      *(uint4*)((char*)sA + ((r * 4 + (ch ^ (r & 3))) << 4)) = va;
      uint4 vb = *(const uint4*)(W1 + (o0 + r) * 1024 + i0 + ch * 8);
      *(uint4*)((char*)sB + ((r * 4 + (ch ^ (r & 3))) << 4)) = vb;
    }
    __syncthreads();
    f16x8 a[4];
#pragma unroll
    for (int m = 0; m < 4; ++m) {
      int r = wm * 64 + m * 16 + l15;
      a[m] = *(const f16x8*)((const char*)sA + ((r * 4 + (g4 ^ (r & 3))) << 4));
    }
#pragma unroll
    for (int n = 0; n < 4; ++n) {
      int r = wn * 64 + n * 16 + l15;
      f16x8 b = *(const f16x8*)((const char*)sB + ((r * 4 + (g4 ^ (r & 3))) << 4));
#pragma unroll
      for (int m = 0; m < 4; ++m)
        acc[m][n] = __builtin_amdgcn_mfma_f32_16x16x32_f16(a[m], b, acc[m][n], 0, 0, 0);
    }
    __syncthreads();
  }
  // max over this block's 128 words
#pragma unroll
  for (int n = 0; n < 4; ++n) {
    float v = -3.4e38f;
#pragma unroll
    for (int m = 0; m < 4; ++m)
#pragma unroll
      for (int j = 0; j < 4; ++j) v = fmaxf(v, acc[m][n][j]);
    v = fmaxf(v, __shfl_xor(v, 16));
    v = fmaxf(v, __shfl_xor(v, 32));
    if (lane < 16) sRed[wm][wn * 64 + n * 16 + l15] = v;
  }
  __syncthreads();
  if (tid < 128)
    part[blockIdx.x * 1024 + o0 + tid] = fmaxf(sRed[0][tid], sRed[1][tid]);
}

// ---------------- k3: reduce partials, lin1+tanh, lin2 ----------------
__global__ __launch_bounds__(256) void k3_rmax(const float* __restrict__ part,
                                               const float* __restrict__ sb,
                                               float* __restrict__ rmax) {
  int o = blockIdx.x * 256 + threadIdx.x;
  float v = -3.4e38f;
  for (int r = 0; r < 32; ++r) v = fmaxf(v, part[r * 1024 + o]);
  rmax[o] = v + sb[o];   // bias constant over words -> add after max
}

__global__ __launch_bounds__(256) void k3_lin1(const float* __restrict__ w,
                                               const float* __restrict__ b,
                                               const float* __restrict__ rmax,
                                               float* __restrict__ h) {
  __shared__ float sR[1024];
  int tid = threadIdx.x;
  for (int i = tid; i < 1024; i += 256) sR[i] = rmax[i];
  __syncthreads();
  int wid = tid >> 6, lane = tid & 63;
  for (int p = 0; p < 8; ++p) {
    int j = blockIdx.x * 32 + p * 4 + wid;   // grid 64 -> j in [0,2048)
    float a = 0.f;
    for (int i = lane; i < 1024; i += 64) a += w[j * 1024 + i] * sR[i];
#pragma unroll
    for (int off = 32; off >= 1; off >>= 1) a += __shfl_xor(a, off);
    if (lane == 0) h[j] = tanhf(a + b[j]);
  }
}

__global__ __launch_bounds__(256) void k3_out(const float* __restrict__ h,
                                              const float* __restrict__ w,
                                              const float* __restrict__ b,
                                              float* __restrict__ out) {
  __shared__ float red0[4], red1[4];
  int tid = threadIdx.x, wid = tid >> 6, lane = tid & 63;
  float a0 = 0.f, a1 = 0.f;
  for (int i = tid; i < 2048; i += 256) {
    float hv = h[i];
    a0 += hv * w[i];
    a1 += hv * w[2048 + i];
  }
#pragma unroll
  for (int off = 32; off >= 1; off >>= 1) {
    a0 += __shfl_xor(a0, off);
    a1 += __shfl_xor(a1, off);
  }
  if (lane == 0) { red0[wid] = a0; red1[wid] = a1; }
  __syncthreads();
  if (tid == 0) {
    out[0] = red0[0] + red0[1] + red0[2] + red0[3] + b[0];
    out[1] = red1[0] + red1[1] + red1[2] + red1[3] + b[1];
  }
}

// ---------------- launcher ----------------
extern "C" void kernel_launch(void* const* d_in, const int* in_sizes, int n_in,
                              void* d_out, int out_size, void* d_ws, size_t ws_size,
                              hipStream_t stream) {
  (void)in_sizes; (void)n_in; (void)out_size; (void)ws_size;
  const int*   words = (const int*)d_in[0];
  const int*   wic   = (const int*)d_in[1];
  const float* wemb  = (const float*)d_in[2];
  const float* cemb  = (const float*)d_in[3];
  const float* ccw   = (const float*)d_in[4];
  const float* ccb   = (const float*)d_in[5];
  const float* csw   = (const float*)d_in[6];
  const float* csb   = (const float*)d_in[7];
  const float* l1w   = (const float*)d_in[8];
  const float* l1b   = (const float*)d_in[9];
  const float* l2w   = (const float*)d_in[10];
  const float* l2b   = (const float*)d_in[11];
  float* out = (float*)d_out;
  char* ws = (char*)d_ws;
  f16* ceT = (f16*)(ws + WS_CET);
  f16* Wc  = (f16*)(ws + WS_WC);
  f16* W1  = (f16*)(ws + WS_W1);
  f16* U   = (f16*)(ws + WS_U);
  float* part = (float*)(ws + WS_PART);
  float* rmax = (float*)(ws + WS_RMAX);
  float* h    = (float*)(ws + WS_H);

  k0_ceT <<<dim3(256),    dim3(512), 0, stream>>>(cemb, ceT);
  k0_wc  <<<dim3(3072),   dim3(256), 0, stream>>>(ccw, Wc);
  k0_w1  <<<dim3(4096),   dim3(256), 0, stream>>>(csw, W1);
  k0_u   <<<dim3(4096),   dim3(256), 0, stream>>>(words, wemb, U);
  k1_conv<<<dim3(512, 4), dim3(256), 0, stream>>>(wic, Wc, ceT, ccb, U);
  k2_sent<<<dim3(32, 8),  dim3(256), 0, stream>>>(U, W1, part);
  k3_rmax<<<dim3(4),      dim3(256), 0, stream>>>(part, csb, rmax);
  k3_lin1<<<dim3(64),     dim3(256), 0, stream>>>(l1w, l1b, rmax, h);
  k3_out <<<dim3(1),      dim3(256), 0, stream>>>(h, l2w, l2b, out);
}

// Round 2
// 633.438 us; speedup vs baseline: 1.1206x; 1.1206x over previous
//
#include <hip/hip_runtime.h>
#include <hip/hip_fp16.h>

typedef _Float16 f16;
typedef __attribute__((ext_vector_type(8))) _Float16 f16x8;
typedef __attribute__((ext_vector_type(4))) float f32x4;

// ---------------- workspace layout (bytes) ----------------
#define WS_CET   0u           // ceT  [256][32][16] f16   = 262144
#define WS_WC    262144u      // Wc   swizzled [4 oblk][16 step][1536 chunks]*16B = 1572864
#define WS_W1    1835008u     // W1   [1024][1024] f16    = 2097152
#define WS_U     3932160u     // U    [4096][1024] f16    = 8388608
#define WS_PART  12320768u    // part [32][1024]  f32     = 131072
#define WS_RMAX  12451840u    // rmax [1024]      f32     = 4096
#define WS_H     12455936u    // h    [2048]      f32     = 8192

// async global->LDS, 16B per lane; LDS dest = uniform base + lane*16
__device__ __forceinline__ void gload16(const void* g, void* l) {
  __builtin_amdgcn_global_load_lds(
      (const __attribute__((address_space(1))) unsigned int*)g,
      (__attribute__((address_space(3))) unsigned int*)l, 16, 0, 0);
}

// ---------------- fused prep ----------------
// b<384: Wc swizzled chunks; b<4480: W1; b<4992: ceT; else: U word half
__global__ __launch_bounds__(256) void k0_prep(
    const int* __restrict__ words, const float* __restrict__ wemb,
    const float* __restrict__ cemb, const float* __restrict__ ccw,
    const float* __restrict__ csw,
    f16* __restrict__ ceT, f16* __restrict__ Wc, f16* __restrict__ W1,
    f16* __restrict__ U)
{
  int b = blockIdx.x, tid = threadIdx.x;
  if (b < 384) {
    // one 16B chunk per thread. LDS position chunk p holds data chunk (p&3)^((o>>1)&3)
    int q = b * 256 + tid;                 // 0..98303
    int oblk = q / 24576;
    int r = q - oblk * 24576;
    int step = r / 1536, p = r - step * 1536;
    int k = p >> 9, ol = (p >> 2) & 127, chp = p & 3;
    int ch = chp ^ ((ol >> 1) & 3);
    int o = oblk * 128 + ol, i0 = step * 32 + ch * 8;
    f16x8 v;
#pragma unroll
    for (int j = 0; j < 8; ++j) v[j] = (f16)ccw[(o * 512 + i0 + j) * 3 + k];
    *(f16x8*)(Wc + (size_t)q * 8) = v;
  } else if (b < 4480) {
    int e = (b - 384) * 256 + tid;         // 1048576
    int o = e >> 10, i = e & 1023;
    W1[e] = (f16)csw[(o * 1024 + i) * 3 + 1];
  } else if (b < 4992) {
    int e = (b - 4480) * 256 + tid;        // 131072
    int c = e >> 9, t = e & 511;
    int m = t >> 5, l = t & 31;
    float v = (c == 0) ? 0.f : cemb[c * 512 + m * 32 + l];
    ceT[c * 512 + l * 16 + m] = (f16)v;    // ceT[c][l][m] = ce[c][m*32+l]
  } else {
    int n = b - 4992;
    int wd = words[n];
    const float* src = wemb + (size_t)wd * 512;
    for (int i = tid; i < 512; i += 256)
      U[n * 1024 + i] = (f16)((wd == 0) ? 0.f : src[i]);
  }
}

// ---------------- k1: char conv + maxpool -> U[n][512..1023] ----------------
// block: 128 o x 16 words (256 cols x ... N=512 cols), 4 waves, each wave m8n8
// (128o x 128col = 4 words). 2-phase pipeline, global_load_lds staging.
__global__ __launch_bounds__(256, 1) void k1_conv(
    const int* __restrict__ wic, const f16* __restrict__ Wc,
    const f16* __restrict__ ceT, const float* __restrict__ bias,
    f16* __restrict__ U)
{
  __shared__ __align__(16) f16 sA[2][12288];   // [3][128][32] as 1536 swz chunks
  __shared__ __align__(16) f16 sB[2][17408];   // [16 w][34 lp][32 i] as 2176 chunks
  __shared__ int sChar[512];
  __shared__ float sBias[128];

  const int tid = threadIdx.x;
  const int w0 = blockIdx.x * 16;
  const int oblk = blockIdx.y;
  const int o0 = oblk * 128;
  const int wid = tid >> 6, lane = tid & 63;
  const int l15 = lane & 15, g4 = lane >> 4;

  sChar[tid] = wic[w0 * 32 + tid];
  sChar[tid + 256] = wic[w0 * 32 + 256 + tid];
  if (tid < 128) sBias[tid] = bias[o0 + tid];
  {  // zero halo rows (lp=0 -> chunks 0..3, lp=33 -> chunks 132..135), both buffers
    int buf = tid >> 7, rem = tid & 127, w = rem >> 3, q = rem & 7;
    int chk = w * 136 + (q < 4 ? q : 128 + q);
    *(uint4*)((char*)sB[buf] + (chk << 4)) = make_uint4(0, 0, 0, 0);
  }
  __syncthreads();   // sChar ready for stgB

  auto stgA = [&](int buf, int step) {
    const f16* src = Wc + ((size_t)(oblk * 16 + step) * 1536 + wid * 384 + lane) * 8;
    f16* dst = sA[buf] + wid * 3072;
#pragma unroll
    for (int c = 0; c < 6; ++c)
      gload16(src + c * 512, dst + c * 512);   // 64 chunks per call
  };
  auto stgB = [&](int buf, int step) {
#pragma unroll
    for (int c = 0; c < 8; ++c) {
      int wl = wid * 4 + (c >> 1), h = c & 1;
      int lp = 1 + h * 16 + (lane >> 2);       // LDS row (halo-shifted)
      int ch = (lane & 3) ^ ((lp >> 1) & 3);   // data chunk at this position
      int cc = sChar[wl * 32 + step * 2 + (ch >> 1)];
      gload16(ceT + cc * 512 + (lp - 1) * 16 + (ch & 1) * 8,
              sB[buf] + (wl * 136 + 4 + h * 64) * 8);
    }
  };

  stgA(0, 0); stgB(0, 0);

  f32x4 acc[8][8];
#pragma unroll
  for (int m = 0; m < 8; ++m)
#pragma unroll
    for (int n = 0; n < 8; ++n) acc[m][n] = (f32x4){0.f, 0.f, 0.f, 0.f};

  __syncthreads();   // stage 0 complete (syncthreads drains vmcnt)

  for (int t = 0; t < 16; ++t) {
    const int cur = t & 1;
    if (t < 15) { stgA(cur ^ 1, t + 1); stgB(cur ^ 1, t + 1); }
    const f16* A = sA[cur];
    const f16* B = sB[cur];
#pragma unroll
    for (int k = 0; k < 3; ++k) {
      f16x8 a[8];
#pragma unroll
      for (int m = 0; m < 8; ++m) {
        int row = m * 16 + l15;
        int pc = g4 ^ ((row >> 1) & 3);
        a[m] = *(const f16x8*)(A + ((k * 128 + row) * 4 + pc) * 8);
      }
#pragma unroll
      for (int n = 0; n < 8; ++n) {
        int wl = wid * 4 + (n >> 1);
        int lp = (n & 1) * 16 + l15 + k;       // halo row = l + tap
        int pc = g4 ^ ((lp >> 1) & 3);
        f16x8 bfr = *(const f16x8*)(B + (wl * 136 + lp * 4 + pc) * 8);
#pragma unroll
        for (int m = 0; m < 8; ++m)
          acc[m][n] = __builtin_amdgcn_mfma_f32_16x16x32_f16(a[m], bfr, acc[m][n], 0, 0, 0);
      }
    }
    __syncthreads();   // next-stage complete AND this buf free to overwrite
  }

  // epilogue: max over l (n-pairs + shfl over l15), +bias
#pragma unroll
  for (int m = 0; m < 8; ++m) {
    float vm[16];
#pragma unroll
    for (int wp = 0; wp < 4; ++wp)
#pragma unroll
      for (int j = 0; j < 4; ++j)
        vm[wp * 4 + j] = fmaxf(acc[m][2 * wp][j], acc[m][2 * wp + 1][j]);
#pragma unroll
    for (int off = 1; off <= 8; off <<= 1)
#pragma unroll
      for (int q = 0; q < 16; ++q)
        vm[q] = fmaxf(vm[q], __shfl_xor(vm[q], off));
    float v = vm[0];
#pragma unroll
    for (int q = 1; q < 16; ++q) v = (l15 == q) ? vm[q] : v;
    int ol = m * 16 + g4 * 4 + (l15 & 3);
    int word = w0 + wid * 4 + (l15 >> 2);
    U[word * 1024 + 512 + o0 + ol] = (f16)(v + sBias[ol]);
  }
}

// ---------------- k2: r = U @ W1^T, column-max over words ----------------
// 128x128 tile, BK=64 (128B rows -> ch^(row&7) swizzle), 2-phase pipeline
__global__ __launch_bounds__(256, 1) void k2_sent(
    const f16* __restrict__ U, const f16* __restrict__ W1,
    float* __restrict__ part)
{
  __shared__ __align__(16) f16 sA[2][8192];
  __shared__ __align__(16) f16 sB[2][8192];
  __shared__ float sRed[2][128];

  const int tid = threadIdx.x;
  const int w0 = blockIdx.x * 128, o0 = blockIdx.y * 128;
  const int wid = tid >> 6, lane = tid & 63;
  const int wm = wid >> 1, wn = wid & 1;
  const int l15 = lane & 15, g4 = lane >> 4;

  auto stg = [&](int buf, int step) {
    int i0 = step * 64;
#pragma unroll
    for (int c = 0; c < 4; ++c) {
      int row = wid * 32 + c * 8 + (lane >> 3);
      int ch = (lane & 7) ^ (row & 7);
      gload16(U  + (size_t)(w0 + row) * 1024 + i0 + ch * 8, sA[buf] + (wid * 32 + c * 8) * 64);
      gload16(W1 + (size_t)(o0 + row) * 1024 + i0 + ch * 8, sB[buf] + (wid * 32 + c * 8) * 64);
    }
  };

  stg(0, 0);
  f32x4 acc[4][4];
#pragma unroll
  for (int m = 0; m < 4; ++m)
#pragma unroll
    for (int n = 0; n < 4; ++n) acc[m][n] = (f32x4){0.f, 0.f, 0.f, 0.f};
  __syncthreads();

  for (int t = 0; t < 16; ++t) {
    const int cur = t & 1;
    if (t < 15) stg(cur ^ 1, t + 1);
#pragma unroll
    for (int s = 0; s < 2; ++s) {
      f16x8 a[4];
#pragma unroll
      for (int m = 0; m < 4; ++m) {
        int row = wm * 64 + m * 16 + l15;
        int pc = (s * 4 + g4) ^ (row & 7);
        a[m] = *(const f16x8*)(sA[cur] + row * 64 + pc * 8);
      }
#pragma unroll
      for (int n = 0; n < 4; ++n) {
        int row = wn * 64 + n * 16 + l15;
        int pc = (s * 4 + g4) ^ (row & 7);
        f16x8 bfr = *(const f16x8*)(sB[cur] + row * 64 + pc * 8);
#pragma unroll
        for (int m = 0; m < 4; ++m)
          acc[m][n] = __builtin_amdgcn_mfma_f32_16x16x32_f16(a[m], bfr, acc[m][n], 0, 0, 0);
      }
    }
    __syncthreads();
  }
  // max over this block's 128 words
#pragma unroll
  for (int n = 0; n < 4; ++n) {
    float v = -3.4e38f;
#pragma unroll
    for (int m = 0; m < 4; ++m)
#pragma unroll
      for (int j = 0; j < 4; ++j) v = fmaxf(v, acc[m][n][j]);
    v = fmaxf(v, __shfl_xor(v, 16));
    v = fmaxf(v, __shfl_xor(v, 32));
    if (lane < 16) sRed[wm][wn * 64 + n * 16 + l15] = v;
  }
  __syncthreads();
  if (tid < 128)
    part[blockIdx.x * 1024 + o0 + tid] = fmaxf(sRed[0][tid], sRed[1][tid]);
}

// ---------------- k3: reduce partials, lin1+tanh, lin2 ----------------
__global__ __launch_bounds__(256) void k3_rmax(const float* __restrict__ part,
                                               const float* __restrict__ sb,
                                               float* __restrict__ rmax) {
  int o = blockIdx.x * 256 + threadIdx.x;
  float v = -3.4e38f;
  for (int r = 0; r < 32; ++r) v = fmaxf(v, part[r * 1024 + o]);
  rmax[o] = v + sb[o];
}

__global__ __launch_bounds__(256) void k3_lin1(const float* __restrict__ w,
                                               const float* __restrict__ b,
                                               const float* __restrict__ rmax,
                                               float* __restrict__ h) {
  __shared__ float sR[1024];
  int tid = threadIdx.x;
  for (int i = tid; i < 1024; i += 256) sR[i] = rmax[i];
  __syncthreads();
  int wid = tid >> 6, lane = tid & 63;
  for (int p = 0; p < 8; ++p) {
    int j = blockIdx.x * 32 + p * 4 + wid;
    float a = 0.f;
    for (int i = lane; i < 1024; i += 64) a += w[j * 1024 + i] * sR[i];
#pragma unroll
    for (int off = 32; off >= 1; off >>= 1) a += __shfl_xor(a, off);
    if (lane == 0) h[j] = tanhf(a + b[j]);
  }
}

__global__ __launch_bounds__(256) void k3_out(const float* __restrict__ h,
                                              const float* __restrict__ w,
                                              const float* __restrict__ b,
                                              float* __restrict__ out) {
  __shared__ float red0[4], red1[4];
  int tid = threadIdx.x, wid = tid >> 6, lane = tid & 63;
  float a0 = 0.f, a1 = 0.f;
  for (int i = tid; i < 2048; i += 256) {
    float hv = h[i];
    a0 += hv * w[i];
    a1 += hv * w[2048 + i];
  }
#pragma unroll
  for (int off = 32; off >= 1; off >>= 1) {
    a0 += __shfl_xor(a0, off);
    a1 += __shfl_xor(a1, off);
  }
  if (lane == 0) { red0[wid] = a0; red1[wid] = a1; }
  __syncthreads();
  if (tid == 0) {
    out[0] = red0[0] + red0[1] + red0[2] + red0[3] + b[0];
    out[1] = red1[0] + red1[1] + red1[2] + red1[3] + b[1];
  }
}

// ---------------- launcher ----------------
extern "C" void kernel_launch(void* const* d_in, const int* in_sizes, int n_in,
                              void* d_out, int out_size, void* d_ws, size_t ws_size,
                              hipStream_t stream) {
  (void)in_sizes; (void)n_in; (void)out_size; (void)ws_size;
  const int*   words = (const int*)d_in[0];
  const int*   wic   = (const int*)d_in[1];
  const float* wemb  = (const float*)d_in[2];
  const float* cemb  = (const float*)d_in[3];
  const float* ccw   = (const float*)d_in[4];
  const float* ccb   = (const float*)d_in[5];
  const float* csw   = (const float*)d_in[6];
  const float* csb   = (const float*)d_in[7];
  const float* l1w   = (const float*)d_in[8];
  const float* l1b   = (const float*)d_in[9];
  const float* l2w   = (const float*)d_in[10];
  const float* l2b   = (const float*)d_in[11];
  float* out = (float*)d_out;
  char* ws = (char*)d_ws;
  f16* ceT = (f16*)(ws + WS_CET);
  f16* Wc  = (f16*)(ws + WS_WC);
  f16* W1  = (f16*)(ws + WS_W1);
  f16* U   = (f16*)(ws + WS_U);
  float* part = (float*)(ws + WS_PART);
  float* rmax = (float*)(ws + WS_RMAX);
  float* h    = (float*)(ws + WS_H);

  k0_prep<<<dim3(9088),   dim3(256), 0, stream>>>(words, wemb, cemb, ccw, csw,
                                                  ceT, Wc, W1, U);
  k1_conv<<<dim3(256, 4), dim3(256), 0, stream>>>(wic, Wc, ceT, ccb, U);
  k2_sent<<<dim3(32, 8),  dim3(256), 0, stream>>>(U, W1, part);
  k3_rmax<<<dim3(4),      dim3(256), 0, stream>>>(part, csb, rmax);
  k3_lin1<<<dim3(64),     dim3(256), 0, stream>>>(l1w, l1b, rmax, h);
  k3_out <<<dim3(1),      dim3(256), 0, stream>>>(h, l2w, l2b, out);
}